// Round 9
// baseline (275.912 us; speedup 1.0000x reference)
//
#include <hip/hip_runtime.h>
#include <math.h>

#define NTOK 65536
#define DIMD 128
#define KCB  2048

typedef unsigned short u16;
typedef __attribute__((ext_vector_type(8))) unsigned short u16x8;
typedef __attribute__((ext_vector_type(8))) __bf16 bf16x8;
typedef __attribute__((ext_vector_type(4))) float f32x4;

union U8 { u16x8 u; bf16x8 b; };

__device__ __forceinline__ u16 f2bf(float f) {
  union { float f; unsigned u; } c; c.f = f;
  unsigned r = c.u + 0x7FFFu + ((c.u >> 16) & 1u);
  return (u16)(r >> 16);
}
__device__ __forceinline__ float bf2f(u16 h) {
  union { unsigned u; float f; } c; c.u = ((unsigned)h) << 16;
  return c.f;
}

__device__ __forceinline__ float block_reduce4(float v, volatile float* sm, int tid) {
  #pragma unroll
  for (int off = 32; off; off >>= 1) v += __shfl_xor(v, off, 64);
  __syncthreads();
  if ((tid & 63) == 0) sm[tid >> 6] = v;
  __syncthreads();
  float r = sm[0] + sm[1] + sm[2] + sm[3];
  __syncthreads();
  return r;
}

// linear tile staging: thread tid covers bytes [tid*16 + i*4096]; dest mirrors source
__device__ __forceinline__ void stage4(const char* srcLane, char* ldsWaveBase) {
  #pragma unroll
  for (int i = 0; i < 4; ++i)
    __builtin_amdgcn_global_load_lds((const __attribute__((address_space(1))) void*)(srcLane + i * 4096),
                                     (__attribute__((address_space(3))) void*)(ldsWaveBase + i * 4096), 16, 0, 0);
}
__device__ __forceinline__ void stage2(const char* srcLane, char* ldsWaveBase) {
  #pragma unroll
  for (int i = 0; i < 2; ++i)
    __builtin_amdgcn_global_load_lds((const __attribute__((address_space(1))) void*)(srcLane + i * 4096),
                                     (__attribute__((address_space(3))) void*)(ldsWaveBase + i * 4096), 16, 0, 0);
}

// ---------------- small kernels ----------------

__global__ __launch_bounds__(256) void k_zero(float* __restrict__ avgp, float* __restrict__ t1,
                                              float* __restrict__ acc3, float* __restrict__ cnt) {
  const int i = blockIdx.x * 256 + threadIdx.x;
  if (i < KCB) { avgp[i] = 0.0f; cnt[i] = 0.0f; }
  if (i == 0) { t1[0] = 0.0f; acc3[0] = 0.0f; acc3[1] = 0.0f; acc3[2] = 0.0f; }
}

// normalize rows of x -> bf16 split halves (one wave per row)
__global__ __launch_bounds__(256) void k_prepx(const float* __restrict__ x, const float* __restrict__ mask,
                                               u16* __restrict__ xh, u16* __restrict__ xl) {
  const int wid = (blockIdx.x * 256 + threadIdx.x) >> 6;
  const int lane = threadIdx.x & 63;
  if (wid >= NTOK) return;
  const float add = (1.0f - mask[wid]) * 1e-6f;
  const float2 v = *(const float2*)(x + (size_t)wid * DIMD + lane * 2);
  const float a0 = v.x + add, a1 = v.y + add;
  float ss = a0 * a0 + a1 * a1;
  #pragma unroll
  for (int off = 32; off; off >>= 1) ss += __shfl_xor(ss, off, 64);
  const float sc = 1.0f / fmaxf(sqrtf(ss), 1e-6f);
  const float f0 = a0 * sc, f1 = a1 * sc;
  const u16 h0 = f2bf(f0), h1 = f2bf(f1);
  const u16 g0 = f2bf(f0 - bf2f(h0)), g1 = f2bf(f1 - bf2f(h1));
  union { u16 s[2]; unsigned u; } wh, wl;
  wh.s[0] = h0; wh.s[1] = h1; wl.s[0] = g0; wl.s[1] = g1;
  *(unsigned*)(xh + (size_t)wid * DIMD + lane * 2) = wh.u;
  *(unsigned*)(xl + (size_t)wid * DIMD + lane * 2) = wl.u;
}

// pack codebook to bf16 H+L in MFMA-fragment order, 32-code tiles:
// tile T in [0,64): bytes [T*16384, +8192) = H frags, [+8192, +16384) = L frags
// frag f = ks*2+nf in [0,8): 64 lanes x 16B; code c = T*32+nf*16+(lane&15), dims d = ks*32+(lane>>4)*8..+8
__global__ __launch_bounds__(256) void k_packcb(const float* __restrict__ cb, u16* __restrict__ cbp) {
  const int gid = blockIdx.x * 256 + threadIdx.x;
  if (gid >= 32768) return;
  const int lane = gid & 63;
  const int f = (gid >> 6) & 7;
  const int T = gid >> 9;
  const int ks = f >> 1, nf = f & 1;
  const int hi = lane >> 4, l15 = lane & 15;
  const int c = T * 32 + nf * 16 + l15;
  const int d0 = ks * 32 + hi * 8;
  const float4 v0 = *(const float4*)(cb + (size_t)c * DIMD + d0);
  const float4 v1 = *(const float4*)(cb + (size_t)c * DIMD + d0 + 4);
  const float e[8] = {v0.x, v0.y, v0.z, v0.w, v1.x, v1.y, v1.z, v1.w};
  union { u16 s[8]; u16x8 u; } oh, ol;
  #pragma unroll
  for (int i = 0; i < 8; ++i) {
    const u16 h = f2bf(e[i]);
    oh.s[i] = h;
    ol.s[i] = f2bf(e[i] - bf2f(h));
  }
  u16* tile = cbp + (size_t)T * 8192;
  *(u16x8*)(tile + (f * 64 + lane) * 8) = oh.u;
  *(u16x8*)(tile + 4096 + (f * 64 + lane) * 8) = ol.u;
}

__global__ __launch_bounds__(256) void k_gather(const float* __restrict__ cb, const float* __restrict__ mask,
                                                const int* __restrict__ rowIdx, float* __restrict__ outQ,
                                                float* __restrict__ outCnt, float* __restrict__ outEnc) {
  const int g = blockIdx.x * 256 + threadIdx.x;
  const int row = g >> 5, l = g & 31;
  if (row >= NTOK) return;
  const int idx = rowIdx[row];
  const float4 v = *(const float4*)(cb + (size_t)idx * DIMD + l * 4);
  *(float4*)(outQ + (size_t)row * DIMD + l * 4) = v;
  if (l == 0) {
    atomicAdd(&outCnt[idx], mask[row]);
    outEnc[row] = (float)idx;
  }
}

// ---------------- MFMA pass 1 (split precision): per-row max / argmax / Z ----------------

__global__ __launch_bounds__(256, 4) void k_pass1(const u16* __restrict__ xh, const u16* __restrict__ xl,
                                                  const u16* __restrict__ cbp,
                                                  float* __restrict__ rowV1, float* __restrict__ rowZ,
                                                  int* __restrict__ rowIdx) {
  __shared__ __align__(16) char Bsmem[32768];  // 2 x (8KB H + 8KB L)
  const int tid = threadIdx.x;
  const int lane = tid & 63, w = tid >> 6;
  const int l15 = lane & 15, hi = lane >> 4;
  const int row0 = blockIdx.x * 64;
  const char* src = (const char*)cbp;

  U8 Ah[4], Al[4];
  {
    const size_t arow = (size_t)(row0 + w * 16 + l15);
    #pragma unroll
    for (int ks = 0; ks < 4; ++ks) {
      Ah[ks].u = *(const u16x8*)(xh + arow * DIMD + ks * 32 + hi * 8);
      Al[ks].u = *(const u16x8*)(xl + arow * DIMD + ks * 32 + hi * 8);
    }
  }

  float v1[4], rs[4];
  int k1[4];
  #pragma unroll
  for (int r = 0; r < 4; ++r) { v1[r] = -1e30f; rs[r] = 0.0f; k1[r] = 0; }

  stage4(src + 0 * 16384 + tid * 16, Bsmem + 0 * 16384 + w * 1024);
  stage4(src + 1 * 16384 + tid * 16, Bsmem + 1 * 16384 + w * 1024);

  for (int t = 0; t < 64; ++t) {
    const int b = t & 1;
    if (t < 62) asm volatile("s_waitcnt vmcnt(4)" ::: "memory");
    else        asm volatile("s_waitcnt vmcnt(0)" ::: "memory");
    __builtin_amdgcn_sched_barrier(0);
    __builtin_amdgcn_s_barrier();
    __builtin_amdgcn_sched_barrier(0);

    const char* base = Bsmem + b * 16384 + lane * 16;
    f32x4 acc[2];
    acc[0] = (f32x4){0.f, 0.f, 0.f, 0.f};
    acc[1] = (f32x4){0.f, 0.f, 0.f, 0.f};

    __builtin_amdgcn_s_setprio(1);
    #pragma unroll
    for (int ks = 0; ks < 4; ++ks) {
      #pragma unroll
      for (int nf = 0; nf < 2; ++nf) {
        U8 bh, bl;
        bh.u = *(const u16x8*)(base + ((ks * 2 + nf) << 10));
        bl.u = *(const u16x8*)(base + 8192 + ((ks * 2 + nf) << 10));
        acc[nf] = __builtin_amdgcn_mfma_f32_16x16x32_bf16(Ah[ks].b, bh.b, acc[nf], 0, 0, 0);
        acc[nf] = __builtin_amdgcn_mfma_f32_16x16x32_bf16(Al[ks].b, bh.b, acc[nf], 0, 0, 0);
        acc[nf] = __builtin_amdgcn_mfma_f32_16x16x32_bf16(Ah[ks].b, bl.b, acc[nf], 0, 0, 0);
      }
    }
    __builtin_amdgcn_s_setprio(0);
    asm volatile("s_waitcnt lgkmcnt(0)" ::: "memory");
    __builtin_amdgcn_sched_barrier(0);
    __builtin_amdgcn_s_barrier();
    __builtin_amdgcn_sched_barrier(0);
    if (t < 62)
      stage4(src + (size_t)(t + 2) * 16384 + tid * 16, Bsmem + b * 16384 + w * 1024);

    // epilogue (registers only) overlaps the prefetch
    const int colbase = t * 32 + l15;
    #pragma unroll
    for (int rg = 0; rg < 4; ++rg) {
      float vv1 = v1[rg];
      int kk1 = k1[rg];
      const float mold = vv1;
      const float x0 = acc[0][rg], x1 = acc[1][rg];
      if (x0 > vv1) { vv1 = x0; kk1 = colbase; }
      if (x1 > vv1) { vv1 = x1; kk1 = colbase + 16; }
      const float mx = fmaxf(x0, x1);
      float z = rs[rg];
      if (__any(vv1 > mold)) z *= __expf(200.f * (mold - vv1));
      if (__any(mx - vv1 > -0.125f)) {
        z += __expf(200.f * (x0 - vv1));
        z += __expf(200.f * (x1 - vv1));
      }
      v1[rg] = vv1; k1[rg] = kk1; rs[rg] = z;
    }
  }

  // cross-lane merge within each 16-lane group
  #pragma unroll
  for (int rg = 0; rg < 4; ++rg) {
    float a1 = v1[rg], az = rs[rg];
    int ak = k1[rg];
    #pragma unroll
    for (int off = 1; off <= 8; off <<= 1) {
      const float o1 = __shfl_xor(a1, off, 64);
      const float oz = __shfl_xor(az, off, 64);
      const int okk = __shfl_xor(ak, off, 64);
      const float nm = fmaxf(a1, o1);
      az = az * __expf((a1 - nm) * 200.f) + oz * __expf((o1 - nm) * 200.f);
      const bool take = (o1 > a1) || (o1 == a1 && okk < ak);
      ak = take ? okk : ak;
      a1 = nm;
    }
    if (l15 == 0) {
      const int row = row0 + w * 16 + hi * 4 + rg;
      rowV1[row] = a1; rowZ[row] = az; rowIdx[row] = ak;
    }
  }
}

// ---------------- MFMA pass 2 (plain bf16): avg_probs column sums + sample-entropy ----------------

__global__ __launch_bounds__(256, 4) void k_pass2(const u16* __restrict__ xh, const u16* __restrict__ cbp,
                                                  const float* __restrict__ mask, const float* __restrict__ rowV1,
                                                  const float* __restrict__ rowZ, float* __restrict__ avgp,
                                                  float* __restrict__ t1g) {
  __shared__ __align__(16) char Bsmem[16384];  // 2 x 8KB H tiles
  __shared__ float ap[KCB];
  __shared__ float sm4[4];
  const int tid = threadIdx.x;
  const int lane = tid & 63, w = tid >> 6;
  const int l15 = lane & 15, hi = lane >> 4;
  const int row0 = blockIdx.x * 64;
  const char* src = (const char*)cbp;

  for (int i = tid; i < KCB; i += 256) ap[i] = 0.0f;

  U8 Ah[4];
  {
    const size_t arow = (size_t)(row0 + w * 16 + l15);
    #pragma unroll
    for (int ks = 0; ks < 4; ++ks)
      Ah[ks].u = *(const u16x8*)(xh + arow * DIMD + ks * 32 + hi * 8);
  }

  // offr = log(mask/Z) - 200*max => p_masked = exp(200*s + offr); t1' = sum p*u'
  float offr[4];
  #pragma unroll
  for (int rg = 0; rg < 4; ++rg) {
    const int row = row0 + w * 16 + hi * 4 + rg;
    const float zim = mask[row] / rowZ[row];
    const float lz = (zim > 0.0f) ? __logf(zim) : -1e30f;
    offr[rg] = lz - 200.f * rowV1[row];
  }
  float t1 = 0.0f;

  stage2(src + 0 * 16384 + tid * 16, Bsmem + 0 * 8192 + w * 1024);
  stage2(src + 1 * 16384 + tid * 16, Bsmem + 1 * 8192 + w * 1024);

  // make ap[] zeroing visible before any wave's epilogue atomics
  __builtin_amdgcn_s_barrier();

  for (int t = 0; t < 64; ++t) {
    const int b = t & 1;
    if (t < 62) asm volatile("s_waitcnt vmcnt(2)" ::: "memory");
    else        asm volatile("s_waitcnt vmcnt(0)" ::: "memory");
    __builtin_amdgcn_sched_barrier(0);
    __builtin_amdgcn_s_barrier();
    __builtin_amdgcn_sched_barrier(0);

    const char* base = Bsmem + b * 8192 + lane * 16;
    f32x4 acc[2];
    acc[0] = (f32x4){0.f, 0.f, 0.f, 0.f};
    acc[1] = (f32x4){0.f, 0.f, 0.f, 0.f};

    __builtin_amdgcn_s_setprio(1);
    #pragma unroll
    for (int ks = 0; ks < 4; ++ks) {
      #pragma unroll
      for (int nf = 0; nf < 2; ++nf) {
        U8 bb;
        bb.u = *(const u16x8*)(base + ((ks * 2 + nf) << 10));
        acc[nf] = __builtin_amdgcn_mfma_f32_16x16x32_bf16(Ah[ks].b, bb.b, acc[nf], 0, 0, 0);
      }
    }
    __builtin_amdgcn_s_setprio(0);
    asm volatile("s_waitcnt lgkmcnt(0)" ::: "memory");
    __builtin_amdgcn_sched_barrier(0);
    __builtin_amdgcn_s_barrier();
    __builtin_amdgcn_sched_barrier(0);
    if (t < 62)
      stage2(src + (size_t)(t + 2) * 16384 + tid * 16, Bsmem + b * 8192 + w * 1024);

    float colsum[2];
    colsum[0] = 0.0f; colsum[1] = 0.0f;
    #pragma unroll
    for (int rg = 0; rg < 4; ++rg) {
      const float u0 = fmaf(acc[0][rg], 200.f, offr[rg]);
      const float u1 = fmaf(acc[1][rg], 200.f, offr[rg]);
      const float umx = fmaxf(u0, u1);
      if (__any(umx > -25.f)) {
        const float p0 = __expf(u0), p1 = __expf(u1);
        colsum[0] += p0; colsum[1] += p1;
        t1 = fmaf(p0, u0, t1);
        t1 = fmaf(p1, u1, t1);
      }
    }
    #pragma unroll
    for (int nf = 0; nf < 2; ++nf) {
      colsum[nf] += __shfl_xor(colsum[nf], 16, 64);
      colsum[nf] += __shfl_xor(colsum[nf], 32, 64);
    }
    if (lane < 16) {
      atomicAdd(&ap[t * 32 + lane], colsum[0]);
      atomicAdd(&ap[t * 32 + 16 + lane], colsum[1]);
    }
  }

  __syncthreads();
  for (int i = tid; i < KCB; i += 256) atomicAdd(&avgp[i], ap[i]);
  #pragma unroll
  for (int off = 32; off; off >>= 1) t1 += __shfl_xor(t1, off, 64);
  if ((tid & 63) == 0) sm4[tid >> 6] = t1;
  __syncthreads();
  if (tid == 0) atomicAdd(t1g, sm4[0] + sm4[1] + sm4[2] + sm4[3]);
}

// ---------------- scalar reductions ----------------

__global__ __launch_bounds__(256) void k_stats(const float* __restrict__ mask, const float* __restrict__ rowV1,
                                               float* __restrict__ acc3) {
  __shared__ float sm[4];
  const int tid = threadIdx.x;
  float msum = 0.f, slat = 0.f;
  for (int n = blockIdx.x * 256 + tid; n < NTOK; n += gridDim.x * 256) {
    const float mk = mask[n];
    msum += mk;
    slat = fmaf(mk, 2.0f - 2.0f * rowV1[n], slat);
  }
  msum = block_reduce4(msum, sm, tid);
  slat = block_reduce4(slat, sm, tid);
  if (tid == 0) {
    atomicAdd(&acc3[0], msum);
    atomicAdd(&acc3[1], slat);
  }
}

__global__ __launch_bounds__(256) void k_final(const float* __restrict__ avgp, const float* __restrict__ t1g,
                                               const float* __restrict__ acc3, float* __restrict__ out3) {
  __shared__ float sm[4];
  const int tid = threadIdx.x;
  const float msum = acc3[0];
  float ae = 0.f;
  for (int k2 = tid; k2 < KCB; k2 += 256) {
    const float a = avgp[k2] / msum;
    ae += a * __logf(a + 1e-5f);
  }
  ae = block_reduce4(ae, sm, tid);
  if (tid == 0) {
    const float sample_entropy = -t1g[0] / msum;  // slogz folded analytically
    const float lat = acc3[1] / (msum + 1e-6f);
    out3[0] = lat;
    out3[1] = lat;
    out3[2] = sample_entropy + ae;
  }
}

// ---------------- launcher ----------------

extern "C" void kernel_launch(void* const* d_in, const int* in_sizes, int n_in,
                              void* d_out, int out_size, void* d_ws, size_t ws_size,
                              hipStream_t stream) {
  const float* x = (const float*)d_in[0];
  const float* mask = (const float*)d_in[1];
  const float* cb = (const float*)d_in[2];

  float* out = (float*)d_out;
  float* outQ = out;
  float* out3 = out + (size_t)NTOK * DIMD;
  float* outCnt = out3 + 3;
  float* outEnc = outCnt + KCB;

  // bf16-split x lives in the quantized output region until k_gather overwrites it
  u16* xh = (u16*)outQ;
  u16* xl = xh + (size_t)NTOK * DIMD;

  float* ws = (float*)d_ws;
  float* rowV1 = ws;                           // N
  float* rowZ = ws + (size_t)NTOK;             // N
  int* rowIdx = (int*)(ws + 2 * (size_t)NTOK); // N
  float* avgp = ws + 3 * (size_t)NTOK;         // K
  float* t1g = avgp + KCB;                     // 1
  float* acc3 = t1g + 1;                       // 3
  u16* cbp = (u16*)(ws + 3 * (size_t)NTOK + KCB + 8);  // K*D*2 u16 fragment-packed H+L

  k_zero<<<(KCB + 255) / 256, 256, 0, stream>>>(avgp, t1g, acc3, outCnt);
  k_prepx<<<(NTOK * 64) / 256, 256, 0, stream>>>(x, mask, xh, xl);
  k_packcb<<<32768 / 256, 256, 0, stream>>>(cb, cbp);
  k_pass1<<<NTOK / 64, 256, 0, stream>>>(xh, xl, cbp, rowV1, rowZ, rowIdx);
  k_pass2<<<NTOK / 64, 256, 0, stream>>>(xh, cbp, mask, rowV1, rowZ, avgp, t1g);
  k_stats<<<64, 256, 0, stream>>>(mask, rowV1, acc3);
  // gather runs after pass2 (outQ aliases xh/xl)
  k_gather<<<(NTOK * 32) / 256, 256, 0, stream>>>(cb, mask, rowIdx, outQ, outCnt, outEnc);
  k_final<<<1, 256, 0, stream>>>(avgp, t1g, acc3, out3);
}

// Round 10
// 247.166 us; speedup vs baseline: 1.1163x; 1.1163x over previous
//
#include <hip/hip_runtime.h>
#include <math.h>

#define NTOK 65536
#define DIMD 128
#define KCB  2048

typedef unsigned short u16;
typedef __attribute__((ext_vector_type(8))) unsigned short u16x8;
typedef __attribute__((ext_vector_type(8))) __bf16 bf16x8;
typedef __attribute__((ext_vector_type(16))) float f32x16;

union U8 { u16x8 u; bf16x8 b; };

__device__ __forceinline__ u16 f2bf(float f) {
  union { float f; unsigned u; } c; c.f = f;
  unsigned r = c.u + 0x7FFFu + ((c.u >> 16) & 1u);
  return (u16)(r >> 16);
}
__device__ __forceinline__ float bf2f(u16 h) {
  union { unsigned u; float f; } c; c.u = ((unsigned)h) << 16;
  return c.f;
}

__device__ __forceinline__ float block_reduce4(float v, volatile float* sm, int tid) {
  #pragma unroll
  for (int off = 32; off; off >>= 1) v += __shfl_xor(v, off, 64);
  __syncthreads();
  if ((tid & 63) == 0) sm[tid >> 6] = v;
  __syncthreads();
  float r = sm[0] + sm[1] + sm[2] + sm[3];
  __syncthreads();
  return r;
}

// linear staging: thread tid covers bytes [tid*16 + i*4096]
__device__ __forceinline__ void stage32k(const char* srcLane, char* ldsWaveBase) {
  #pragma unroll
  for (int i = 0; i < 8; ++i)
    __builtin_amdgcn_global_load_lds((const __attribute__((address_space(1))) void*)(srcLane + i * 4096),
                                     (__attribute__((address_space(3))) void*)(ldsWaveBase + i * 4096), 16, 0, 0);
}
__device__ __forceinline__ void stage16k(const char* srcLane, char* ldsWaveBase) {
  #pragma unroll
  for (int i = 0; i < 4; ++i)
    __builtin_amdgcn_global_load_lds((const __attribute__((address_space(1))) void*)(srcLane + i * 4096),
                                     (__attribute__((address_space(3))) void*)(ldsWaveBase + i * 4096), 16, 0, 0);
}

#define MFMA32(a, b, c) __builtin_amdgcn_mfma_f32_32x32x16_bf16((a), (b), (c), 0, 0, 0)

// ---------------- small kernels ----------------

__global__ __launch_bounds__(256) void k_zero(float* __restrict__ avgp, float* __restrict__ t1,
                                              float* __restrict__ acc3, float* __restrict__ cnt) {
  const int i = blockIdx.x * 256 + threadIdx.x;
  if (i < KCB) { avgp[i] = 0.0f; cnt[i] = 0.0f; }
  if (i == 0) { t1[0] = 0.0f; acc3[0] = 0.0f; acc3[1] = 0.0f; acc3[2] = 0.0f; }
}

// normalize rows of x -> bf16 split halves (one wave per row)
__global__ __launch_bounds__(256) void k_prepx(const float* __restrict__ x, const float* __restrict__ mask,
                                               u16* __restrict__ xh, u16* __restrict__ xl) {
  const int wid = (blockIdx.x * 256 + threadIdx.x) >> 6;
  const int lane = threadIdx.x & 63;
  if (wid >= NTOK) return;
  const float add = (1.0f - mask[wid]) * 1e-6f;
  const float2 v = *(const float2*)(x + (size_t)wid * DIMD + lane * 2);
  const float a0 = v.x + add, a1 = v.y + add;
  float ss = a0 * a0 + a1 * a1;
  #pragma unroll
  for (int off = 32; off; off >>= 1) ss += __shfl_xor(ss, off, 64);
  const float sc = 1.0f / fmaxf(sqrtf(ss), 1e-6f);
  const float f0 = a0 * sc, f1 = a1 * sc;
  const u16 h0 = f2bf(f0), h1 = f2bf(f1);
  const u16 g0 = f2bf(f0 - bf2f(h0)), g1 = f2bf(f1 - bf2f(h1));
  union { u16 s[2]; unsigned u; } wh, wl;
  wh.s[0] = h0; wh.s[1] = h1; wl.s[0] = g0; wl.s[1] = g1;
  *(unsigned*)(xh + (size_t)wid * DIMD + lane * 2) = wh.u;
  *(unsigned*)(xl + (size_t)wid * DIMD + lane * 2) = wl.u;
}

// pack codebook to bf16 H+L in 32x32-MFMA fragment order, 64-code tiles:
// tile T in [0,32): bytes [T*32768, +16384) = H frags, [+16384, +32768) = L frags
// frag (g,s), g in 0..1, s in 0..7: 64 lanes x 16B at (g*8+s)*1024
// lane l: code c = T*64 + g*32 + (l&31); k elems = s*16 + (l>>5)*8 .. +8
__global__ __launch_bounds__(256) void k_packcb(const float* __restrict__ cb, u16* __restrict__ cbp) {
  const int gid = blockIdx.x * 256 + threadIdx.x;
  if (gid >= 32768) return;
  const int lane = gid & 63;
  const int s = (gid >> 6) & 7;
  const int g = (gid >> 9) & 1;
  const int T = gid >> 10;
  const int c = T * 64 + g * 32 + (lane & 31);
  const int k0 = s * 16 + (lane >> 5) * 8;
  const float4 v0 = *(const float4*)(cb + (size_t)c * DIMD + k0);
  const float4 v1 = *(const float4*)(cb + (size_t)c * DIMD + k0 + 4);
  const float e[8] = {v0.x, v0.y, v0.z, v0.w, v1.x, v1.y, v1.z, v1.w};
  union { u16 s_[8]; u16x8 u; } oh, ol;
  #pragma unroll
  for (int i = 0; i < 8; ++i) {
    const u16 h = f2bf(e[i]);
    oh.s_[i] = h;
    ol.s_[i] = f2bf(e[i] - bf2f(h));
  }
  u16* tile = cbp + (size_t)T * 16384;  // 32KB = 16384 u16
  const int fo = ((g * 8 + s) * 64 + lane) * 8;
  *(u16x8*)(tile + fo) = oh.u;
  *(u16x8*)(tile + 8192 + fo) = ol.u;
}

__global__ __launch_bounds__(256) void k_gather(const float* __restrict__ cb, const float* __restrict__ mask,
                                                const int* __restrict__ rowIdx, float* __restrict__ outQ,
                                                float* __restrict__ outCnt, float* __restrict__ outEnc) {
  const int g = blockIdx.x * 256 + threadIdx.x;
  const int row = g >> 5, l = g & 31;
  if (row >= NTOK) return;
  const int idx = rowIdx[row];
  const float4 v = *(const float4*)(cb + (size_t)idx * DIMD + l * 4);
  *(float4*)(outQ + (size_t)row * DIMD + l * 4) = v;
  if (l == 0) {
    atomicAdd(&outCnt[idx], mask[row]);
    outEnc[row] = (float)idx;
  }
}

// ---------------- MFMA pass 1 (split precision, 32x32): per-row max / argmax / Z ----------------

__global__ __launch_bounds__(256, 2) void k_pass1(const u16* __restrict__ xh, const u16* __restrict__ xl,
                                                  const u16* __restrict__ cbp,
                                                  float* __restrict__ rowV1, float* __restrict__ rowZ,
                                                  int* __restrict__ rowIdx) {
  __shared__ __align__(16) char Bsmem[65536];  // 2 x 32KB tiles
  const int tid = threadIdx.x;
  const int lane = tid & 63, w = tid >> 6;
  const int row0 = blockIdx.x * 128;
  const char* src = (const char*)cbp;

  // A fragments: row = lane&31, k = s*16 + (lane>>5)*8 .. +8
  U8 Ah[8], Al[8];
  {
    const size_t arow = (size_t)(row0 + w * 32 + (lane & 31));
    const int kh = (lane >> 5) * 8;
    #pragma unroll
    for (int s = 0; s < 8; ++s) {
      Ah[s].u = *(const u16x8*)(xh + arow * DIMD + s * 16 + kh);
      Al[s].u = *(const u16x8*)(xl + arow * DIMD + s * 16 + kh);
    }
  }

  float v1[16], rs[16];
  int k1[16];
  #pragma unroll
  for (int i = 0; i < 16; ++i) { v1[i] = -1e30f; rs[i] = 0.0f; k1[i] = 0; }

  stage32k(src + tid * 16, Bsmem + w * 1024);  // tile 0 -> buf0

  for (int t = 0; t < 32; ++t) {
    const int b = t & 1;
    asm volatile("s_waitcnt vmcnt(0) lgkmcnt(0)" ::: "memory");
    __builtin_amdgcn_sched_barrier(0);
    __builtin_amdgcn_s_barrier();
    __builtin_amdgcn_sched_barrier(0);
    if (t < 31)
      stage32k(src + (size_t)(t + 1) * 32768 + tid * 16, Bsmem + (b ^ 1) * 32768 + w * 1024);

    const char* base = Bsmem + b * 32768 + lane * 16;
    f32x16 accA0 = {}, accA1 = {}, accB0 = {}, accB1 = {};

    __builtin_amdgcn_s_setprio(1);
    #pragma unroll
    for (int s = 0; s < 8; ++s) {
      U8 bh0, bh1, bl0, bl1;
      bh0.u = *(const u16x8*)(base + (s << 10));
      bh1.u = *(const u16x8*)(base + ((8 + s) << 10));
      bl0.u = *(const u16x8*)(base + 16384 + (s << 10));
      bl1.u = *(const u16x8*)(base + 16384 + ((8 + s) << 10));
      accA0 = MFMA32(Ah[s].b, bh0.b, accA0);
      accA1 = MFMA32(Ah[s].b, bh1.b, accA1);
      accB0 = MFMA32(Ah[s].b, bl0.b, accB0);
      accB1 = MFMA32(Ah[s].b, bl1.b, accB1);
      accA0 = MFMA32(Al[s].b, bh0.b, accA0);
      accA1 = MFMA32(Al[s].b, bh1.b, accA1);
    }
    __builtin_amdgcn_s_setprio(0);

    // epilogue (registers only) overlaps the prefetch
    const int colc0 = t * 64 + (lane & 31);
    #pragma unroll
    for (int i = 0; i < 16; ++i) {
      const float x0 = accA0[i] + accB0[i];
      const float x1 = accA1[i] + accB1[i];
      float vv = v1[i];
      int kk = k1[i];
      const float mold = vv;
      if (x0 > vv) { vv = x0; kk = colc0; }
      if (x1 > vv) { vv = x1; kk = colc0 + 32; }
      float z = rs[i];
      if (__any(vv > mold)) z *= __expf(200.f * (mold - vv));
      if (__any(fmaxf(x0, x1) - vv > -0.125f)) {
        z += __expf(200.f * (x0 - vv));
        z += __expf(200.f * (x1 - vv));
      }
      v1[i] = vv; k1[i] = kk; rs[i] = z;
    }
  }

  // cross-lane merge within each 32-lane half (bit5 of lane = row-half, untouched)
  #pragma unroll
  for (int i = 0; i < 16; ++i) {
    float a1 = v1[i], az = rs[i];
    int ak = k1[i];
    #pragma unroll
    for (int off = 1; off <= 16; off <<= 1) {
      const float o1 = __shfl_xor(a1, off, 64);
      const float oz = __shfl_xor(az, off, 64);
      const int okk = __shfl_xor(ak, off, 64);
      const float nm = fmaxf(a1, o1);
      az = az * __expf((a1 - nm) * 200.f) + oz * __expf((o1 - nm) * 200.f);
      const bool take = (o1 > a1) || (o1 == a1 && okk < ak);
      ak = take ? okk : ak;
      a1 = nm;
    }
    if ((lane & 31) == 0) {
      const int row = row0 + w * 32 + (i & 3) + 8 * (i >> 2) + 4 * (lane >> 5);
      rowV1[row] = a1; rowZ[row] = az; rowIdx[row] = ak;
    }
  }
}

// ---------------- MFMA pass 2 (plain bf16, 32x32): avg_probs column sums + sample-entropy ----------------

__global__ __launch_bounds__(256, 2) void k_pass2(const u16* __restrict__ xh, const u16* __restrict__ cbp,
                                                  const float* __restrict__ mask, const float* __restrict__ rowV1,
                                                  const float* __restrict__ rowZ, float* __restrict__ avgp,
                                                  float* __restrict__ t1g) {
  __shared__ __align__(16) char Bsmem[32768];  // 2 x 16KB H tiles
  __shared__ float ap[KCB];
  __shared__ float sm4[4];
  const int tid = threadIdx.x;
  const int lane = tid & 63, w = tid >> 6;
  const int row0 = blockIdx.x * 128;
  const char* src = (const char*)cbp;

  for (int i = tid; i < KCB; i += 256) ap[i] = 0.0f;

  U8 Ah[8];
  {
    const size_t arow = (size_t)(row0 + w * 32 + (lane & 31));
    const int kh = (lane >> 5) * 8;
    #pragma unroll
    for (int s = 0; s < 8; ++s)
      Ah[s].u = *(const u16x8*)(xh + arow * DIMD + s * 16 + kh);
  }

  // offr = log(mask/Z) - 200*max => p_masked = exp(200*s + offr); t1' = sum p*u'
  float offr[16];
  #pragma unroll
  for (int i = 0; i < 16; ++i) {
    const int row = row0 + w * 32 + (i & 3) + 8 * (i >> 2) + 4 * (lane >> 5);
    const float zim = mask[row] / rowZ[row];
    const float lz = (zim > 0.0f) ? __logf(zim) : -1e30f;
    offr[i] = lz - 200.f * rowV1[row];
  }
  float t1 = 0.0f;

  stage16k(src + tid * 16, Bsmem + w * 1024);  // tile 0 H-half -> buf0

  for (int t = 0; t < 32; ++t) {
    const int b = t & 1;
    asm volatile("s_waitcnt vmcnt(0) lgkmcnt(0)" ::: "memory");
    __builtin_amdgcn_sched_barrier(0);
    __builtin_amdgcn_s_barrier();
    __builtin_amdgcn_sched_barrier(0);
    if (t < 31)
      stage16k(src + (size_t)(t + 1) * 32768 + tid * 16, Bsmem + (b ^ 1) * 16384 + w * 1024);

    const char* base = Bsmem + b * 16384 + lane * 16;
    f32x16 acc0 = {}, acc1 = {};

    __builtin_amdgcn_s_setprio(1);
    #pragma unroll
    for (int s = 0; s < 8; ++s) {
      U8 bh0, bh1;
      bh0.u = *(const u16x8*)(base + (s << 10));
      bh1.u = *(const u16x8*)(base + ((8 + s) << 10));
      acc0 = MFMA32(Ah[s].b, bh0.b, acc0);
      acc1 = MFMA32(Ah[s].b, bh1.b, acc1);
    }
    __builtin_amdgcn_s_setprio(0);

    float cs0 = 0.0f, cs1 = 0.0f;
    #pragma unroll
    for (int i = 0; i < 16; ++i) {
      const float u0 = fmaf(acc0[i], 200.f, offr[i]);
      const float u1 = fmaf(acc1[i], 200.f, offr[i]);
      if (__any(fmaxf(u0, u1) > -25.f)) {
        const float p0 = __expf(u0), p1 = __expf(u1);
        cs0 += p0; cs1 += p1;
        t1 = fmaf(p0, u0, t1);
        t1 = fmaf(p1, u1, t1);
      }
    }
    cs0 += __shfl_xor(cs0, 32, 64);
    cs1 += __shfl_xor(cs1, 32, 64);
    if (lane < 32) {
      atomicAdd(&ap[t * 64 + lane], cs0);
      atomicAdd(&ap[t * 64 + 32 + lane], cs1);
    }
  }

  __syncthreads();
  for (int i = tid; i < KCB; i += 256) atomicAdd(&avgp[i], ap[i]);
  #pragma unroll
  for (int off = 32; off; off >>= 1) t1 += __shfl_xor(t1, off, 64);
  if ((tid & 63) == 0) sm4[tid >> 6] = t1;
  __syncthreads();
  if (tid == 0) atomicAdd(t1g, sm4[0] + sm4[1] + sm4[2] + sm4[3]);
}

// ---------------- scalar reductions ----------------

__global__ __launch_bounds__(256) void k_stats(const float* __restrict__ mask, const float* __restrict__ rowV1,
                                               float* __restrict__ acc3) {
  __shared__ float sm[4];
  const int tid = threadIdx.x;
  float msum = 0.f, slat = 0.f;
  for (int n = blockIdx.x * 256 + tid; n < NTOK; n += gridDim.x * 256) {
    const float mk = mask[n];
    msum += mk;
    slat = fmaf(mk, 2.0f - 2.0f * rowV1[n], slat);
  }
  msum = block_reduce4(msum, sm, tid);
  slat = block_reduce4(slat, sm, tid);
  if (tid == 0) {
    atomicAdd(&acc3[0], msum);
    atomicAdd(&acc3[1], slat);
  }
}

__global__ __launch_bounds__(256) void k_final(const float* __restrict__ avgp, const float* __restrict__ t1g,
                                               const float* __restrict__ acc3, float* __restrict__ out3) {
  __shared__ float sm[4];
  const int tid = threadIdx.x;
  const float msum = acc3[0];
  float ae = 0.f;
  for (int k2 = tid; k2 < KCB; k2 += 256) {
    const float a = avgp[k2] / msum;
    ae += a * __logf(a + 1e-5f);
  }
  ae = block_reduce4(ae, sm, tid);
  if (tid == 0) {
    const float sample_entropy = -t1g[0] / msum;  // slogz folded analytically
    const float lat = acc3[1] / (msum + 1e-6f);
    out3[0] = lat;
    out3[1] = lat;
    out3[2] = sample_entropy + ae;
  }
}

// ---------------- launcher ----------------

extern "C" void kernel_launch(void* const* d_in, const int* in_sizes, int n_in,
                              void* d_out, int out_size, void* d_ws, size_t ws_size,
                              hipStream_t stream) {
  const float* x = (const float*)d_in[0];
  const float* mask = (const float*)d_in[1];
  const float* cb = (const float*)d_in[2];

  float* out = (float*)d_out;
  float* outQ = out;
  float* out3 = out + (size_t)NTOK * DIMD;
  float* outCnt = out3 + 3;
  float* outEnc = outCnt + KCB;

  // bf16-split x lives in the quantized output region until k_gather overwrites it
  u16* xh = (u16*)outQ;
  u16* xl = xh + (size_t)NTOK * DIMD;

  float* ws = (float*)d_ws;
  float* rowV1 = ws;                           // N
  float* rowZ = ws + (size_t)NTOK;             // N
  int* rowIdx = (int*)(ws + 2 * (size_t)NTOK); // N
  float* avgp = ws + 3 * (size_t)NTOK;         // K
  float* t1g = avgp + KCB;                     // 1
  float* acc3 = t1g + 1;                       // 3
  u16* cbp = (u16*)(ws + 3 * (size_t)NTOK + KCB + 8);  // K*D*2 u16 fragment-packed H+L

  k_zero<<<(KCB + 255) / 256, 256, 0, stream>>>(avgp, t1g, acc3, outCnt);
  k_prepx<<<(NTOK * 64) / 256, 256, 0, stream>>>(x, mask, xh, xl);
  k_packcb<<<32768 / 256, 256, 0, stream>>>(cb, cbp);
  k_pass1<<<NTOK / 128, 256, 0, stream>>>(xh, xl, cbp, rowV1, rowZ, rowIdx);
  k_pass2<<<NTOK / 128, 256, 0, stream>>>(xh, cbp, mask, rowV1, rowZ, avgp, t1g);
  k_stats<<<64, 256, 0, stream>>>(mask, rowV1, acc3);
  // gather runs after pass2 (outQ aliases xh/xl)
  k_gather<<<(NTOK * 32) / 256, 256, 0, stream>>>(cb, mask, rowIdx, outQ, outCnt, outEnc);
  k_final<<<1, 256, 0, stream>>>(avgp, t1g, acc3, out3);
}